// Round 9
// baseline (651.574 us; speedup 1.0000x reference)
//
#include <hip/hip_runtime.h>
#include <hip/hip_fp16.h>
#include <math.h>

// Problem constants: B=1, N=512, FN=8, FE=1, E=32, D0=14, 8 frames.
#define NN 512

typedef _Float16 f16x8 __attribute__((ext_vector_type(8)));
typedef float    f32x4 __attribute__((ext_vector_type(4)));

// ---------------------------------------------------------------------------
// Manual grid barrier (device-scope). Monotone counter, no reset: barrier k
// waits until counter >= 1024*(k+1). Counter zeroed by hipMemsetAsync before
// each launch. atomicAdd is device-scope (cross-XCD) by default; __threadfence
// = agent-scope fence (L2 writeback on release / invalidate on acquire).
// SAFETY: requires all 1024 blocks co-resident — guaranteed by
// __launch_bounds__(256,4): VGPR<=128 -> 4 blocks/CU x 256 CU = 1024.
// ---------------------------------------------------------------------------
__device__ __forceinline__ void grid_barrier(unsigned* cnt, unsigned target) {
    __syncthreads();
    if (threadIdx.x == 0) {
        __threadfence();                 // release: drain this XCD's L2
        atomicAdd(cnt, 1u);
        while (atomicAdd(cnt, 0u) < target)
            __builtin_amdgcn_s_sleep(7);
        __threadfence();                 // acquire: invalidate stale cache
    }
    __syncthreads();
}

// ---------------------------------------------------------------------------
// Analytic 3x3 symmetric eigendecomposition (double). Ascending eigenvalues.
// Sign ambiguity cancelled by the 8-op frame averaging.
// ---------------------------------------------------------------------------
__device__ __forceinline__ void eig3_sym(const double A[3][3], double V[3][3]) {
    const double a00 = A[0][0], a11 = A[1][1], a22 = A[2][2];
    const double a01 = A[0][1], a02 = A[0][2], a12 = A[1][2];
    double p1 = a01*a01 + a02*a02 + a12*a12;
    if (p1 < 1e-30) {
        double d[3] = {a00, a11, a22};
        int idx[3] = {0, 1, 2};
        for (int a = 0; a < 2; ++a) for (int b = a+1; b < 3; ++b)
            if (d[idx[b]] < d[idx[a]]) { int t = idx[a]; idx[a] = idx[b]; idx[b] = t; }
        for (int r = 0; r < 3; ++r) for (int c = 0; c < 3; ++c)
            V[r][c] = (r == idx[c]) ? 1.0 : 0.0;
        return;
    }
    double q = (a00 + a11 + a22) / 3.0;
    double b00 = a00 - q, b11 = a11 - q, b22 = a22 - q;
    double p2 = b00*b00 + b11*b11 + b22*b22 + 2.0 * p1;
    double p = sqrt(p2 / 6.0);
    double inv_p = 1.0 / p;
    double c00 = b00*inv_p, c11 = b11*inv_p, c22 = b22*inv_p;
    double c01 = a01*inv_p, c02 = a02*inv_p, c12 = a12*inv_p;
    double detB = c00*(c11*c22 - c12*c12) - c01*(c01*c22 - c12*c02)
                + c02*(c01*c12 - c11*c02);
    double r = fmin(1.0, fmax(-1.0, detB * 0.5));
    double phi = acos(r) / 3.0;
    double lam2 = q + 2.0 * p * cos(phi);
    double lam0 = q + 2.0 * p * cos(phi + 2.0943951023931953);
    double vs[2][3]; double lams[2] = {lam0, lam2};
    for (int e = 0; e < 2; ++e) {
        double l = lams[e];
        double r0[3] = {a00 - l, a01, a02};
        double r1[3] = {a01, a11 - l, a12};
        double r2[3] = {a02, a12, a22 - l};
        double c0[3] = {r0[1]*r1[2]-r0[2]*r1[1], r0[2]*r1[0]-r0[0]*r1[2], r0[0]*r1[1]-r0[1]*r1[0]};
        double c1[3] = {r0[1]*r2[2]-r0[2]*r2[1], r0[2]*r2[0]-r0[0]*r2[2], r0[0]*r2[1]-r0[1]*r2[0]};
        double c2[3] = {r1[1]*r2[2]-r1[2]*r2[1], r1[2]*r2[0]-r1[0]*r2[2], r1[0]*r2[1]-r1[1]*r2[0]};
        double n0 = c0[0]*c0[0]+c0[1]*c0[1]+c0[2]*c0[2];
        double n1 = c1[0]*c1[0]+c1[1]*c1[1]+c1[2]*c1[2];
        double n2 = c2[0]*c2[0]+c2[1]*c2[1]+c2[2]*c2[2];
        double* best = c0; double nb = n0;
        if (n1 > nb) { best = c1; nb = n1; }
        if (n2 > nb) { best = c2; nb = n2; }
        double inv = 1.0 / sqrt(nb);
        vs[e][0] = best[0]*inv; vs[e][1] = best[1]*inv; vs[e][2] = best[2]*inv;
    }
    double vm[3] = {vs[1][1]*vs[0][2]-vs[1][2]*vs[0][1],
                    vs[1][2]*vs[0][0]-vs[1][0]*vs[0][2],
                    vs[1][0]*vs[0][1]-vs[1][1]*vs[0][0]};
    double nm = 1.0 / sqrt(vm[0]*vm[0]+vm[1]*vm[1]+vm[2]*vm[2]);
    for (int rr = 0; rr < 3; ++rr) {
        V[rr][0] = vs[0][rr];
        V[rr][1] = vm[rr]*nm;
        V[rr][2] = vs[1][rr];
    }
}

// ---------------------------------------------------------------------------
// Per-block redundant frame computation (deterministic, identical results).
// ---------------------------------------------------------------------------
__device__ __forceinline__ void compute_frame(const float* __restrict__ x,
                                              float* __restrict__ sFR,
                                              double (*red)[9]) {
    const int t = threadIdx.x;
    double s[9] = {0,0,0,0,0,0,0,0,0};
    for (int n = t; n < NN; n += 256) {
        double X = x[n*3+0], Y = x[n*3+1], Z = x[n*3+2];
        s[0]+=X; s[1]+=Y; s[2]+=Z;
        s[3]+=X*X; s[4]+=X*Y; s[5]+=X*Z; s[6]+=Y*Y; s[7]+=Y*Z; s[8]+=Z*Z;
    }
    #pragma unroll
    for (int m = 1; m < 64; m <<= 1) {
        #pragma unroll
        for (int q = 0; q < 9; ++q) s[q] += __shfl_xor(s[q], m);
    }
    const int wave = t >> 6, lane = t & 63;
    if (lane == 0) {
        #pragma unroll
        for (int q = 0; q < 9; ++q) red[wave][q] = s[q];
    }
    __syncthreads();
    if (t == 0) {
        double S[9];
        #pragma unroll
        for (int q = 0; q < 9; ++q) S[q] = red[0][q]+red[1][q]+red[2][q]+red[3][q];
        double cx = S[0]/512.0, cy = S[1]/512.0, cz = S[2]/512.0;
        double A[3][3];
        A[0][0]=S[3]-512.0*cx*cx; A[0][1]=S[4]-512.0*cx*cy; A[0][2]=S[5]-512.0*cx*cz;
        A[1][1]=S[6]-512.0*cy*cy; A[1][2]=S[7]-512.0*cy*cz; A[2][2]=S[8]-512.0*cz*cz;
        A[1][0]=A[0][1]; A[2][0]=A[0][2]; A[2][1]=A[1][2];
        double V[3][3];
        eig3_sym(A, V);
        sFR[0] = (float)cx; sFR[1] = (float)cy; sFR[2] = (float)cz;
        for (int r = 0; r < 3; ++r)
            for (int c = 0; c < 3; ++c)
                sFR[3 + r*3 + c] = (float)V[r][c];
    }
    __syncthreads();
}

// ---------------------------------------------------------------------------
// One edge-MLP unit (as round 7). Unit g in [0,2048): o=g>>8, i-pair=g&255.
// Wave w: i=i0+(w&1), jh=w>>1. Tail on waves 0,1.
// ---------------------------------------------------------------------------
template<int D, bool NEXT>
__device__ __forceinline__ void edge_unit(
    int g, int wv, int lane,
    const _Float16* __restrict__ PJF, const _Float16* __restrict__ PIH,
    const _Float16* __restrict__ WEH, const _Float16* __restrict__ W2F,
    const float* __restrict__ edge, const float* __restrict__ h,
    const float* __restrict__ eb2, const float* __restrict__ nw1,
    const float* __restrict__ nb1, const float* __restrict__ nw2,
    const float* __restrict__ nb2, float* __restrict__ hout,
    const float* __restrict__ ew1n, const float* __restrict__ eb1n,
    _Float16* __restrict__ PJFn, _Float16* __restrict__ PIn,
    float (*sAgg)[32])
{
    const int o = g >> 8;
    const int i = ((g & 255) << 1) + (wv & 1);
    const int jh = wv >> 1;
    const int row = (o << 9) | i;
    const int l15 = lane & 15;
    const int kbase = (lane >> 4) * 8;

    const f16x8 pi8 = *(const f16x8*)(PIH + row * 32 + kbase);
    const f16x8 we8 = *(const f16x8*)(WEH + kbase);
    const f16x8 bfrag0 = *(const f16x8*)(W2F + lane * 16);
    const f16x8 bfrag1 = *(const f16x8*)(W2F + lane * 16 + 8);
    const float b2v0 = eb2[l15], b2v1 = eb2[l15 + 16];
    const f16x8 z8 = {0,0,0,0,0,0,0,0};
    const f32x4 z4 = {0.f, 0.f, 0.f, 0.f};
    const f32x4 bias0 = {b2v0, b2v0, b2v0, b2v0};
    const f32x4 bias1 = {b2v1, b2v1, b2v1, b2v1};
    f32x4 aggv0 = z4, aggv1 = z4;

    const float* edge_i = edge + (i << 9) + (jh << 8);
    const _Float16* pjw = PJF + (size_t)o * 16384 + ((jh << 4) * 64 + lane) * 8;

    #pragma unroll
    for (int u = 0; u < 16; ++u) {
        const f16x8 pj8 = *(const f16x8*)(pjw + u * 512);
        const _Float16 eh = (_Float16)edge_i[u * 16 + l15];
        const f16x8 e8 = {eh, eh, eh, eh, eh, eh, eh, eh};
        f16x8 m = e8 * we8 + (pj8 + pi8);
        m = __builtin_elementwise_max(m, z8);
        f32x4 c0 = __builtin_amdgcn_mfma_f32_16x16x32_f16(m, bfrag0, z4, 0, 0, 0);
        aggv0 += __builtin_elementwise_max(c0 + bias0, z4);
        f32x4 c1 = __builtin_amdgcn_mfma_f32_16x16x32_f16(m, bfrag1, z4, 0, 0, 0);
        aggv1 += __builtin_elementwise_max(c1 + bias1, z4);
    }
    float agg0 = (aggv0[0] + aggv0[1]) + (aggv0[2] + aggv0[3]);
    float agg1 = (aggv1[0] + aggv1[1]) + (aggv1[2] + aggv1[3]);
    agg0 += __shfl_xor(agg0, 16); agg0 += __shfl_xor(agg0, 32);
    agg1 += __shfl_xor(agg1, 16); agg1 += __shfl_xor(agg1, 32);
    if (lane < 16) { sAgg[wv][l15] = agg0; sAgg[wv][16 + l15] = agg1; }
    __syncthreads();

    if (wv < 2) {
        const int c2 = lane & 31;
        const float red2 = sAgg[wv][c2] + sAgg[wv + 2][c2];
        const float* hr = h + row * D;
        float acc = nb1[c2];
        #pragma unroll
        for (int k = 0; k < D; ++k) acc = fmaf(hr[k], nw1[k * 32 + c2], acc);
        #pragma unroll
        for (int k = 0; k < 32; ++k)
            acc = fmaf(__shfl(red2, k, 32), nw1[(D + k) * 32 + c2], acc);
        const float dn = fmaxf(acc, 0.f);
        float outv = nb2[c2];
        #pragma unroll
        for (int k = 0; k < 32; ++k)
            outv = fmaf(__shfl(dn, k, 32), nw2[k * 32 + c2], outv);
        if (lane < 32) hout[row * 32 + c2] = outv;
        if (NEXT) {
            float pj1 = 0.f, pi1 = eb1n[c2];
            #pragma unroll
            for (int k = 0; k < 32; ++k) {
                const float hk = __shfl(outv, k, 32);
                pj1 = fmaf(hk, ew1n[(1 + k) * 32 + c2], pj1);
                pi1 = fmaf(hk, ew1n[(33 + k) * 32 + c2], pi1);
            }
            if (lane < 32) {
                PIn[row * 32 + c2] = (_Float16)pi1;
                const int fl = (i & 15) | ((c2 >> 3) << 4);
                PJFn[(((o << 5) + (i >> 4)) * 64 + fl) * 8 + (c2 & 7)] = (_Float16)pj1;
            }
        }
    }
}

// ---------------------------------------------------------------------------
struct Params {
    const float *x, *v, *nf;
    const float *e0w1, *e0b1, *e0w2, *e0b2, *n0w1, *n0b1, *n0w2, *n0b2;
    const float *e1w1, *e1b1, *e1w2, *e1b2, *n1w1, *n1b1, *n1w2, *n1b2;
    const float *dw1, *db1, *dw2, *db2, *vw1, *vb1, *vw2, *vb2;
    const float *edge;
    unsigned *CNT;
    float *FRg, *H0, *HA, *HB;
    _Float16 *PJF0, *PIH0, *PJF1, *PIH1, *WEH0, *WEH1, *W2F0, *W2F1;
    float *out_h, *out_edge, *out_x, *out_v;
};

// ---------------------------------------------------------------------------
// Whole network, one regular dispatch. 1024 blocks x 256 thr, 4 blocks/CU
// guaranteed co-resident (VGPR<=128) -> manual grid barrier is deadlock-free.
// ---------------------------------------------------------------------------
__global__ void __launch_bounds__(256, 4) mega_kernel(Params P) {
    __shared__ double red[4][9];
    __shared__ float sFR[12];
    __shared__ float sAgg[4][32];
    __shared__ float sSo[8][6];

    const int b = blockIdx.x;
    const int t = threadIdx.x;
    const int wv = t >> 6, lane = t & 63;

    // ======================= Phase A =======================
    if (b < 512) {
        compute_frame(P.x, sFR, red);
        if (b == 0 && t < 12) P.FRg[t] = sFR[t];
        const int c = t & 31;
        const int row = b * 8 + (t >> 5);
        const int o = row >> 9, j = row & 511;
        float hrow[14];
        float xc0 = P.x[j*3+0] - sFR[0], xc1 = P.x[j*3+1] - sFR[1], xc2 = P.x[j*3+2] - sFR[2];
        float v0 = P.v[j*3+0], v1 = P.v[j*3+1], v2 = P.v[j*3+2];
        #pragma unroll
        for (int i = 0; i < 3; ++i) {
            float sgn = ((o >> (2 - i)) & 1) ? -1.f : 1.f;
            float px = sFR[3+0*3+i]*xc0 + sFR[3+1*3+i]*xc1 + sFR[3+2*3+i]*xc2;
            float pv = sFR[3+0*3+i]*v0  + sFR[3+1*3+i]*v1  + sFR[3+2*3+i]*v2;
            hrow[i]     = sgn * px;
            hrow[3 + i] = sgn * pv;
        }
        #pragma unroll
        for (int k = 0; k < 8; ++k) hrow[6 + k] = P.nf[j*8 + k];
        if (c < 14) P.H0[row * 14 + c] = hrow[c];
        float pj = 0.f, pi = P.e0b1[c];
        #pragma unroll
        for (int k = 0; k < 14; ++k) {
            pj = fmaf(hrow[k], P.e0w1[(1 + k) * 32 + c], pj);
            pi = fmaf(hrow[k], P.e0w1[(15 + k) * 32 + c], pi);
        }
        P.PIH0[row * 32 + c] = (_Float16)pi;
        const int fl = (j & 15) | ((c >> 3) << 4);
        P.PJF0[(((o << 5) + (j >> 4)) * 64 + fl) * 8 + (c & 7)] = (_Float16)pj;
    } else {
        // Edge passthrough: 512 blocks x 256 thr x float2 = 262144 floats.
        const int idx = (b - 512) * 256 + t;
        ((float2*)P.out_edge)[idx] = ((const float2*)P.edge)[idx];
        if (b == 1023) {
            const int l15 = lane & 15, kb = (lane >> 4) * 8;
            if (wv == 1) {
                #pragma unroll
                for (int e = 0; e < 8; ++e) {
                    P.W2F0[lane*16 + e]     = (_Float16)P.e0w2[(kb+e)*32 + l15];
                    P.W2F0[lane*16 + 8 + e] = (_Float16)P.e0w2[(kb+e)*32 + l15 + 16];
                }
            } else if (wv == 2) {
                #pragma unroll
                for (int e = 0; e < 8; ++e) {
                    P.W2F1[lane*16 + e]     = (_Float16)P.e1w2[(kb+e)*32 + l15];
                    P.W2F1[lane*16 + 8 + e] = (_Float16)P.e1w2[(kb+e)*32 + l15 + 16];
                }
            } else if (wv == 3 && lane < 32) {
                P.WEH0[lane] = (_Float16)P.e0w1[lane];
                P.WEH1[lane] = (_Float16)P.e1w1[lane];
            }
        }
    }
    grid_barrier(P.CNT, 1024u);

    // ======================= Phase B: edge layer 0 (D=14, fuses L1 pre) ====
    #pragma unroll 1
    for (int u = 0; u < 2; ++u) {
        edge_unit<14, true>(b + (u << 10), wv, lane,
                            P.PJF0, P.PIH0, P.WEH0, P.W2F0, P.edge, P.H0,
                            P.e0b2, P.n0w1, P.n0b1, P.n0w2, P.n0b2, P.HA,
                            P.e1w1, P.e1b1, P.PJF1, P.PIH1, sAgg);
        __syncthreads();
    }
    grid_barrier(P.CNT, 2048u);

    // ======================= Phase C: edge layer 1 (D=32) ==================
    #pragma unroll 1
    for (int u = 0; u < 2; ++u) {
        edge_unit<32, false>(b + (u << 10), wv, lane,
                             P.PJF1, P.PIH1, P.WEH1, P.W2F1, P.edge, P.HA,
                             P.e1b2, P.n1w1, P.n1b1, P.n1w2, P.n1b2, P.HB,
                             nullptr, nullptr, nullptr, nullptr, sAgg);
        __syncthreads();
    }
    grid_barrier(P.CNT, 3072u);

    // ======================= Phase D: decoder + outputs ====================
    if (b >= 512) return;
    const int n = b;
    const int c = lane & 31;
    #pragma unroll
    for (int q = 0; q < 2; ++q) {
        const int o = (wv << 1) | q;
        const int row = (o << 9) | n;
        float rh = fmaxf(P.HB[row * 32 + c], 0.f);
        float acc = P.db1[c];
        #pragma unroll
        for (int k = 0; k < 32; ++k)
            acc = fmaf(__shfl(rh, k, 32), P.dw1[k * 32 + c], acc);
        float s = fmaxf(acc, 0.f);
        #pragma unroll
        for (int m = 0; m < 6; ++m) {
            float p = s * P.dw2[c * 6 + m];
            p += __shfl_xor(p, 1); p += __shfl_xor(p, 2); p += __shfl_xor(p, 4);
            p += __shfl_xor(p, 8); p += __shfl_xor(p, 16);
            if (lane == 0) sSo[o][m] = p + P.db2[m];
        }
    }
    __syncthreads();
    if (wv) return;

    float hm = 0.f;
    #pragma unroll
    for (int o = 0; o < 8; ++o) hm += P.HB[((o << 9) | n) * 32 + c];
    hm *= 0.125f;
    if (lane < 32) P.out_h[n * 32 + c] = hm;
    float rh = fmaxf(hm, 0.f);
    float acc = P.vb1[c];
    #pragma unroll
    for (int k = 0; k < 32; ++k)
        acc = fmaf(__shfl(rh, k, 32), P.vw1[k * 32 + c], acc);
    float t1 = fmaxf(acc, 0.f);
    float p = t1 * P.vw2[c];
    p += __shfl_xor(p, 1); p += __shfl_xor(p, 2); p += __shfl_xor(p, 4);
    p += __shfl_xor(p, 8); p += __shfl_xor(p, 16);
    float coef = p + P.vb2[0];
    if (lane < 3) {
        int i = lane;
        float dx = 0.f, dv = 0.f;
        #pragma unroll
        for (int o = 0; o < 8; ++o) {
            #pragma unroll
            for (int j = 0; j < 3; ++j) {
                float sgn = ((o >> (2 - j)) & 1) ? -1.f : 1.f;
                float f = sgn * P.FRg[3 + i * 3 + j];
                dx = fmaf(f, sSo[o][j], dx);
                dv = fmaf(f, sSo[o][3 + j], dv);
            }
        }
        dx *= 0.125f; dv *= 0.125f;
        float vout = P.v[n * 3 + i] + dv;
        P.out_v[n * 3 + i] = vout;
        P.out_x[n * 3 + i] = P.x[n * 3 + i] + vout * coef + dx;
    }
}

// ---------------------------------------------------------------------------
extern "C" void kernel_launch(void* const* d_in, const int* in_sizes, int n_in,
                              void* d_out, int out_size, void* d_ws, size_t ws_size,
                              hipStream_t stream) {
    char* wsb = (char*)d_ws;
    float* out = (float*)d_out;

    Params P;
    P.x    = (const float*)d_in[2];
    P.v    = (const float*)d_in[3];
    P.nf   = (const float*)d_in[0];
    P.edge = (const float*)d_in[1];
    P.e0w1 = (const float*)d_in[4];  P.e0b1 = (const float*)d_in[5];
    P.e0w2 = (const float*)d_in[6];  P.e0b2 = (const float*)d_in[7];
    P.n0w1 = (const float*)d_in[8];  P.n0b1 = (const float*)d_in[9];
    P.n0w2 = (const float*)d_in[10]; P.n0b2 = (const float*)d_in[11];
    P.e1w1 = (const float*)d_in[12]; P.e1b1 = (const float*)d_in[13];
    P.e1w2 = (const float*)d_in[14]; P.e1b2 = (const float*)d_in[15];
    P.n1w1 = (const float*)d_in[16]; P.n1b1 = (const float*)d_in[17];
    P.n1w2 = (const float*)d_in[18]; P.n1b2 = (const float*)d_in[19];
    P.dw1  = (const float*)d_in[20]; P.db1  = (const float*)d_in[21];
    P.dw2  = (const float*)d_in[22]; P.db2  = (const float*)d_in[23];
    P.vw1  = (const float*)d_in[24]; P.vb1  = (const float*)d_in[25];
    P.vw2  = (const float*)d_in[26]; P.vb2  = (const float*)d_in[27];

    P.CNT  = (unsigned*)wsb;                       // 256 B (barrier counter)
    P.FRg  = (float*)(wsb + 256);                  // 48 B
    P.H0   = (float*)(wsb + 512);                  // 229376 B
    P.HA   = (float*)(wsb + 512 + 229376);         // 524288 B
    P.HB   = (float*)(wsb + 512 + 229376 + 524288);
    char* p = wsb + 512 + 229376 + 524288 + 524288;
    P.PJF0 = (_Float16*)p;  p += 262144;
    P.PIH0 = (_Float16*)p;  p += 262144;
    P.PJF1 = (_Float16*)p;  p += 262144;
    P.PIH1 = (_Float16*)p;  p += 262144;
    P.WEH0 = (_Float16*)p;  p += 256;
    P.WEH1 = (_Float16*)p;  p += 256;
    P.W2F0 = (_Float16*)p;  p += 2048;
    P.W2F1 = (_Float16*)p;  p += 2048;

    P.out_h    = out;
    P.out_edge = out + 16384;
    P.out_x    = out + 278528;
    P.out_v    = out + 280064;

    // Zero the barrier counter (d_ws is poisoned 0xAA before every launch).
    hipMemsetAsync(P.CNT, 0, 256, stream);
    mega_kernel<<<1024, 256, 0, stream>>>(P);
}

// Round 10
// 648.777 us; speedup vs baseline: 1.0043x; 1.0043x over previous
//
#include <hip/hip_runtime.h>
#include <hip/hip_fp16.h>
#include <math.h>

// Problem constants: B=1, N=512, FN=8, FE=1, E=32, D0=14, 8 frames.
#define NN 512

typedef _Float16 f16x8 __attribute__((ext_vector_type(8)));
typedef float    f32x4 __attribute__((ext_vector_type(4)));

// ---------------------------------------------------------------------------
// Manual grid barrier (device-scope). Monotone counter, no reset: barrier k
// waits until counter >= 1024*(k+1). Counter zeroed by hipMemsetAsync.
// ROUND-10 FIX: spin with relaxed agent-scope atomic LOAD (no RMW) — round 9
// spun with atomicAdd(cnt,0), whose 4.5M serialized RMWs cost ~500 us
// (WRITE_SIZE=288MB was the smoking gun).
// SAFETY: all 1024 blocks co-resident (VGPR<=128 via launch_bounds -> 4/CU,
// confirmed by round 9's Occupancy=47.8% = 16/32 waves).
// ---------------------------------------------------------------------------
__device__ __forceinline__ void grid_barrier(unsigned* cnt, unsigned target) {
    __syncthreads();
    if (threadIdx.x == 0) {
        __threadfence();                 // release: publish our writes (agent)
        __hip_atomic_fetch_add(cnt, 1u, __ATOMIC_RELAXED, __HIP_MEMORY_SCOPE_AGENT);
        while (__hip_atomic_load(cnt, __ATOMIC_RELAXED, __HIP_MEMORY_SCOPE_AGENT) < target)
            __builtin_amdgcn_s_sleep(7);
        __threadfence();                 // acquire: invalidate stale cache
    }
    __syncthreads();
}

// ---------------------------------------------------------------------------
// Analytic 3x3 symmetric eigendecomposition (double). Ascending eigenvalues.
// Sign ambiguity cancelled by the 8-op frame averaging.
// ---------------------------------------------------------------------------
__device__ __forceinline__ void eig3_sym(const double A[3][3], double V[3][3]) {
    const double a00 = A[0][0], a11 = A[1][1], a22 = A[2][2];
    const double a01 = A[0][1], a02 = A[0][2], a12 = A[1][2];
    double p1 = a01*a01 + a02*a02 + a12*a12;
    if (p1 < 1e-30) {
        double d[3] = {a00, a11, a22};
        int idx[3] = {0, 1, 2};
        for (int a = 0; a < 2; ++a) for (int b = a+1; b < 3; ++b)
            if (d[idx[b]] < d[idx[a]]) { int t = idx[a]; idx[a] = idx[b]; idx[b] = t; }
        for (int r = 0; r < 3; ++r) for (int c = 0; c < 3; ++c)
            V[r][c] = (r == idx[c]) ? 1.0 : 0.0;
        return;
    }
    double q = (a00 + a11 + a22) / 3.0;
    double b00 = a00 - q, b11 = a11 - q, b22 = a22 - q;
    double p2 = b00*b00 + b11*b11 + b22*b22 + 2.0 * p1;
    double p = sqrt(p2 / 6.0);
    double inv_p = 1.0 / p;
    double c00 = b00*inv_p, c11 = b11*inv_p, c22 = b22*inv_p;
    double c01 = a01*inv_p, c02 = a02*inv_p, c12 = a12*inv_p;
    double detB = c00*(c11*c22 - c12*c12) - c01*(c01*c22 - c12*c02)
                + c02*(c01*c12 - c11*c02);
    double r = fmin(1.0, fmax(-1.0, detB * 0.5));
    double phi = acos(r) / 3.0;
    double lam2 = q + 2.0 * p * cos(phi);
    double lam0 = q + 2.0 * p * cos(phi + 2.0943951023931953);
    double vs[2][3]; double lams[2] = {lam0, lam2};
    for (int e = 0; e < 2; ++e) {
        double l = lams[e];
        double r0[3] = {a00 - l, a01, a02};
        double r1[3] = {a01, a11 - l, a12};
        double r2[3] = {a02, a12, a22 - l};
        double c0[3] = {r0[1]*r1[2]-r0[2]*r1[1], r0[2]*r1[0]-r0[0]*r1[2], r0[0]*r1[1]-r0[1]*r1[0]};
        double c1[3] = {r0[1]*r2[2]-r0[2]*r2[1], r0[2]*r2[0]-r0[0]*r2[2], r0[0]*r2[1]-r0[1]*r2[0]};
        double c2[3] = {r1[1]*r2[2]-r1[2]*r2[1], r1[2]*r2[0]-r1[0]*r2[2], r1[0]*r2[1]-r1[1]*r2[0]};
        double n0 = c0[0]*c0[0]+c0[1]*c0[1]+c0[2]*c0[2];
        double n1 = c1[0]*c1[0]+c1[1]*c1[1]+c1[2]*c1[2];
        double n2 = c2[0]*c2[0]+c2[1]*c2[1]+c2[2]*c2[2];
        double* best = c0; double nb = n0;
        if (n1 > nb) { best = c1; nb = n1; }
        if (n2 > nb) { best = c2; nb = n2; }
        double inv = 1.0 / sqrt(nb);
        vs[e][0] = best[0]*inv; vs[e][1] = best[1]*inv; vs[e][2] = best[2]*inv;
    }
    double vm[3] = {vs[1][1]*vs[0][2]-vs[1][2]*vs[0][1],
                    vs[1][2]*vs[0][0]-vs[1][0]*vs[0][2],
                    vs[1][0]*vs[0][1]-vs[1][1]*vs[0][0]};
    double nm = 1.0 / sqrt(vm[0]*vm[0]+vm[1]*vm[1]+vm[2]*vm[2]);
    for (int rr = 0; rr < 3; ++rr) {
        V[rr][0] = vs[0][rr];
        V[rr][1] = vm[rr]*nm;
        V[rr][2] = vs[1][rr];
    }
}

// ---------------------------------------------------------------------------
// Per-block redundant frame computation (deterministic, identical results).
// ---------------------------------------------------------------------------
__device__ __forceinline__ void compute_frame(const float* __restrict__ x,
                                              float* __restrict__ sFR,
                                              double (*red)[9]) {
    const int t = threadIdx.x;
    double s[9] = {0,0,0,0,0,0,0,0,0};
    for (int n = t; n < NN; n += 256) {
        double X = x[n*3+0], Y = x[n*3+1], Z = x[n*3+2];
        s[0]+=X; s[1]+=Y; s[2]+=Z;
        s[3]+=X*X; s[4]+=X*Y; s[5]+=X*Z; s[6]+=Y*Y; s[7]+=Y*Z; s[8]+=Z*Z;
    }
    #pragma unroll
    for (int m = 1; m < 64; m <<= 1) {
        #pragma unroll
        for (int q = 0; q < 9; ++q) s[q] += __shfl_xor(s[q], m);
    }
    const int wave = t >> 6, lane = t & 63;
    if (lane == 0) {
        #pragma unroll
        for (int q = 0; q < 9; ++q) red[wave][q] = s[q];
    }
    __syncthreads();
    if (t == 0) {
        double S[9];
        #pragma unroll
        for (int q = 0; q < 9; ++q) S[q] = red[0][q]+red[1][q]+red[2][q]+red[3][q];
        double cx = S[0]/512.0, cy = S[1]/512.0, cz = S[2]/512.0;
        double A[3][3];
        A[0][0]=S[3]-512.0*cx*cx; A[0][1]=S[4]-512.0*cx*cy; A[0][2]=S[5]-512.0*cx*cz;
        A[1][1]=S[6]-512.0*cy*cy; A[1][2]=S[7]-512.0*cy*cz; A[2][2]=S[8]-512.0*cz*cz;
        A[1][0]=A[0][1]; A[2][0]=A[0][2]; A[2][1]=A[1][2];
        double V[3][3];
        eig3_sym(A, V);
        sFR[0] = (float)cx; sFR[1] = (float)cy; sFR[2] = (float)cz;
        for (int r = 0; r < 3; ++r)
            for (int c = 0; c < 3; ++c)
                sFR[3 + r*3 + c] = (float)V[r][c];
    }
    __syncthreads();
}

// ---------------------------------------------------------------------------
// One edge-MLP unit. Unit g in [0,2048): o=g>>8, i-pair=g&255.
// Wave w: i=i0+(w&1), jh=w>>1. Tail on waves 0,1.
// ---------------------------------------------------------------------------
template<int D, bool NEXT>
__device__ __forceinline__ void edge_unit(
    int g, int wv, int lane,
    const _Float16* __restrict__ PJF, const _Float16* __restrict__ PIH,
    const _Float16* __restrict__ WEH, const _Float16* __restrict__ W2F,
    const float* __restrict__ edge, const float* __restrict__ h,
    const float* __restrict__ eb2, const float* __restrict__ nw1,
    const float* __restrict__ nb1, const float* __restrict__ nw2,
    const float* __restrict__ nb2, float* __restrict__ hout,
    const float* __restrict__ ew1n, const float* __restrict__ eb1n,
    _Float16* __restrict__ PJFn, _Float16* __restrict__ PIn,
    float (*sAgg)[32])
{
    const int o = g >> 8;
    const int i = ((g & 255) << 1) + (wv & 1);
    const int jh = wv >> 1;
    const int row = (o << 9) | i;
    const int l15 = lane & 15;
    const int kbase = (lane >> 4) * 8;

    const f16x8 pi8 = *(const f16x8*)(PIH + row * 32 + kbase);
    const f16x8 we8 = *(const f16x8*)(WEH + kbase);
    const f16x8 bfrag0 = *(const f16x8*)(W2F + lane * 16);
    const f16x8 bfrag1 = *(const f16x8*)(W2F + lane * 16 + 8);
    const float b2v0 = eb2[l15], b2v1 = eb2[l15 + 16];
    const f16x8 z8 = {0,0,0,0,0,0,0,0};
    const f32x4 z4 = {0.f, 0.f, 0.f, 0.f};
    const f32x4 bias0 = {b2v0, b2v0, b2v0, b2v0};
    const f32x4 bias1 = {b2v1, b2v1, b2v1, b2v1};
    f32x4 aggv0 = z4, aggv1 = z4;

    const float* edge_i = edge + (i << 9) + (jh << 8);
    const _Float16* pjw = PJF + (size_t)o * 16384 + ((jh << 4) * 64 + lane) * 8;

    #pragma unroll
    for (int u = 0; u < 16; ++u) {
        const f16x8 pj8 = *(const f16x8*)(pjw + u * 512);
        const _Float16 eh = (_Float16)edge_i[u * 16 + l15];
        const f16x8 e8 = {eh, eh, eh, eh, eh, eh, eh, eh};
        f16x8 m = e8 * we8 + (pj8 + pi8);
        m = __builtin_elementwise_max(m, z8);
        f32x4 c0 = __builtin_amdgcn_mfma_f32_16x16x32_f16(m, bfrag0, z4, 0, 0, 0);
        aggv0 += __builtin_elementwise_max(c0 + bias0, z4);
        f32x4 c1 = __builtin_amdgcn_mfma_f32_16x16x32_f16(m, bfrag1, z4, 0, 0, 0);
        aggv1 += __builtin_elementwise_max(c1 + bias1, z4);
    }
    float agg0 = (aggv0[0] + aggv0[1]) + (aggv0[2] + aggv0[3]);
    float agg1 = (aggv1[0] + aggv1[1]) + (aggv1[2] + aggv1[3]);
    agg0 += __shfl_xor(agg0, 16); agg0 += __shfl_xor(agg0, 32);
    agg1 += __shfl_xor(agg1, 16); agg1 += __shfl_xor(agg1, 32);
    if (lane < 16) { sAgg[wv][l15] = agg0; sAgg[wv][16 + l15] = agg1; }
    __syncthreads();

    if (wv < 2) {
        const int c2 = lane & 31;
        const float red2 = sAgg[wv][c2] + sAgg[wv + 2][c2];
        const float* hr = h + row * D;
        float acc = nb1[c2];
        #pragma unroll
        for (int k = 0; k < D; ++k) acc = fmaf(hr[k], nw1[k * 32 + c2], acc);
        #pragma unroll
        for (int k = 0; k < 32; ++k)
            acc = fmaf(__shfl(red2, k, 32), nw1[(D + k) * 32 + c2], acc);
        const float dn = fmaxf(acc, 0.f);
        float outv = nb2[c2];
        #pragma unroll
        for (int k = 0; k < 32; ++k)
            outv = fmaf(__shfl(dn, k, 32), nw2[k * 32 + c2], outv);
        if (lane < 32) hout[row * 32 + c2] = outv;
        if (NEXT) {
            float pj1 = 0.f, pi1 = eb1n[c2];
            #pragma unroll
            for (int k = 0; k < 32; ++k) {
                const float hk = __shfl(outv, k, 32);
                pj1 = fmaf(hk, ew1n[(1 + k) * 32 + c2], pj1);
                pi1 = fmaf(hk, ew1n[(33 + k) * 32 + c2], pi1);
            }
            if (lane < 32) {
                PIn[row * 32 + c2] = (_Float16)pi1;
                const int fl = (i & 15) | ((c2 >> 3) << 4);
                PJFn[(((o << 5) + (i >> 4)) * 64 + fl) * 8 + (c2 & 7)] = (_Float16)pj1;
            }
        }
    }
}

// ---------------------------------------------------------------------------
struct Params {
    const float *x, *v, *nf;
    const float *e0w1, *e0b1, *e0w2, *e0b2, *n0w1, *n0b1, *n0w2, *n0b2;
    const float *e1w1, *e1b1, *e1w2, *e1b2, *n1w1, *n1b1, *n1w2, *n1b2;
    const float *dw1, *db1, *dw2, *db2, *vw1, *vb1, *vw2, *vb2;
    const float *edge;
    unsigned *CNT;
    float *FRg, *H0, *HA, *HB;
    _Float16 *PJF0, *PIH0, *PJF1, *PIH1, *WEH0, *WEH1, *W2F0, *W2F1;
    float *out_h, *out_edge, *out_x, *out_v;
};

// ---------------------------------------------------------------------------
// Whole network, one regular dispatch. 1024 blocks x 256 thr, 4 blocks/CU
// co-resident (VGPR<=128) -> manual grid barrier is deadlock-free.
// ---------------------------------------------------------------------------
__global__ void __launch_bounds__(256, 4) mega_kernel(Params P) {
    __shared__ double red[4][9];
    __shared__ float sFR[12];
    __shared__ float sAgg[4][32];
    __shared__ float sSo[8][6];

    const int b = blockIdx.x;
    const int t = threadIdx.x;
    const int wv = t >> 6, lane = t & 63;

    // ======================= Phase A =======================
    if (b < 512) {
        compute_frame(P.x, sFR, red);
        if (b == 0 && t < 12) P.FRg[t] = sFR[t];
        const int c = t & 31;
        const int row = b * 8 + (t >> 5);
        const int o = row >> 9, j = row & 511;
        float hrow[14];
        float xc0 = P.x[j*3+0] - sFR[0], xc1 = P.x[j*3+1] - sFR[1], xc2 = P.x[j*3+2] - sFR[2];
        float v0 = P.v[j*3+0], v1 = P.v[j*3+1], v2 = P.v[j*3+2];
        #pragma unroll
        for (int i = 0; i < 3; ++i) {
            float sgn = ((o >> (2 - i)) & 1) ? -1.f : 1.f;
            float px = sFR[3+0*3+i]*xc0 + sFR[3+1*3+i]*xc1 + sFR[3+2*3+i]*xc2;
            float pv = sFR[3+0*3+i]*v0  + sFR[3+1*3+i]*v1  + sFR[3+2*3+i]*v2;
            hrow[i]     = sgn * px;
            hrow[3 + i] = sgn * pv;
        }
        #pragma unroll
        for (int k = 0; k < 8; ++k) hrow[6 + k] = P.nf[j*8 + k];
        if (c < 14) P.H0[row * 14 + c] = hrow[c];
        float pj = 0.f, pi = P.e0b1[c];
        #pragma unroll
        for (int k = 0; k < 14; ++k) {
            pj = fmaf(hrow[k], P.e0w1[(1 + k) * 32 + c], pj);
            pi = fmaf(hrow[k], P.e0w1[(15 + k) * 32 + c], pi);
        }
        P.PIH0[row * 32 + c] = (_Float16)pi;
        const int fl = (j & 15) | ((c >> 3) << 4);
        P.PJF0[(((o << 5) + (j >> 4)) * 64 + fl) * 8 + (c & 7)] = (_Float16)pj;
    } else {
        // Edge passthrough: 512 blocks x 256 thr x float2 = 262144 floats.
        const int idx = (b - 512) * 256 + t;
        ((float2*)P.out_edge)[idx] = ((const float2*)P.edge)[idx];
        if (b == 1023) {
            const int l15 = lane & 15, kb = (lane >> 4) * 8;
            if (wv == 1) {
                #pragma unroll
                for (int e = 0; e < 8; ++e) {
                    P.W2F0[lane*16 + e]     = (_Float16)P.e0w2[(kb+e)*32 + l15];
                    P.W2F0[lane*16 + 8 + e] = (_Float16)P.e0w2[(kb+e)*32 + l15 + 16];
                }
            } else if (wv == 2) {
                #pragma unroll
                for (int e = 0; e < 8; ++e) {
                    P.W2F1[lane*16 + e]     = (_Float16)P.e1w2[(kb+e)*32 + l15];
                    P.W2F1[lane*16 + 8 + e] = (_Float16)P.e1w2[(kb+e)*32 + l15 + 16];
                }
            } else if (wv == 3 && lane < 32) {
                P.WEH0[lane] = (_Float16)P.e0w1[lane];
                P.WEH1[lane] = (_Float16)P.e1w1[lane];
            }
        }
    }
    grid_barrier(P.CNT, 1024u);

    // ======================= Phase B: edge layer 0 (D=14, fuses L1 pre) ====
    #pragma unroll 1
    for (int u = 0; u < 2; ++u) {
        edge_unit<14, true>(b + (u << 10), wv, lane,
                            P.PJF0, P.PIH0, P.WEH0, P.W2F0, P.edge, P.H0,
                            P.e0b2, P.n0w1, P.n0b1, P.n0w2, P.n0b2, P.HA,
                            P.e1w1, P.e1b1, P.PJF1, P.PIH1, sAgg);
        __syncthreads();
    }
    grid_barrier(P.CNT, 2048u);

    // ======================= Phase C: edge layer 1 (D=32) ==================
    #pragma unroll 1
    for (int u = 0; u < 2; ++u) {
        edge_unit<32, false>(b + (u << 10), wv, lane,
                             P.PJF1, P.PIH1, P.WEH1, P.W2F1, P.edge, P.HA,
                             P.e1b2, P.n1w1, P.n1b1, P.n1w2, P.n1b2, P.HB,
                             nullptr, nullptr, nullptr, nullptr, sAgg);
        __syncthreads();
    }
    grid_barrier(P.CNT, 3072u);

    // ======================= Phase D: decoder + outputs ====================
    if (b >= 512) return;
    const int n = b;
    const int c = lane & 31;
    #pragma unroll
    for (int q = 0; q < 2; ++q) {
        const int o = (wv << 1) | q;
        const int row = (o << 9) | n;
        float rh = fmaxf(P.HB[row * 32 + c], 0.f);
        float acc = P.db1[c];
        #pragma unroll
        for (int k = 0; k < 32; ++k)
            acc = fmaf(__shfl(rh, k, 32), P.dw1[k * 32 + c], acc);
        float s = fmaxf(acc, 0.f);
        #pragma unroll
        for (int m = 0; m < 6; ++m) {
            float p = s * P.dw2[c * 6 + m];
            p += __shfl_xor(p, 1); p += __shfl_xor(p, 2); p += __shfl_xor(p, 4);
            p += __shfl_xor(p, 8); p += __shfl_xor(p, 16);
            if (lane == 0) sSo[o][m] = p + P.db2[m];
        }
    }
    __syncthreads();
    if (wv) return;

    float hm = 0.f;
    #pragma unroll
    for (int o = 0; o < 8; ++o) hm += P.HB[((o << 9) | n) * 32 + c];
    hm *= 0.125f;
    if (lane < 32) P.out_h[n * 32 + c] = hm;
    float rh = fmaxf(hm, 0.f);
    float acc = P.vb1[c];
    #pragma unroll
    for (int k = 0; k < 32; ++k)
        acc = fmaf(__shfl(rh, k, 32), P.vw1[k * 32 + c], acc);
    float t1 = fmaxf(acc, 0.f);
    float p = t1 * P.vw2[c];
    p += __shfl_xor(p, 1); p += __shfl_xor(p, 2); p += __shfl_xor(p, 4);
    p += __shfl_xor(p, 8); p += __shfl_xor(p, 16);
    float coef = p + P.vb2[0];
    if (lane < 3) {
        int i = lane;
        float dx = 0.f, dv = 0.f;
        #pragma unroll
        for (int o = 0; o < 8; ++o) {
            #pragma unroll
            for (int j = 0; j < 3; ++j) {
                float sgn = ((o >> (2 - j)) & 1) ? -1.f : 1.f;
                float f = sgn * P.FRg[3 + i * 3 + j];
                dx = fmaf(f, sSo[o][j], dx);
                dv = fmaf(f, sSo[o][3 + j], dv);
            }
        }
        dx *= 0.125f; dv *= 0.125f;
        float vout = P.v[n * 3 + i] + dv;
        P.out_v[n * 3 + i] = vout;
        P.out_x[n * 3 + i] = P.x[n * 3 + i] + vout * coef + dx;
    }
}

// ---------------------------------------------------------------------------
extern "C" void kernel_launch(void* const* d_in, const int* in_sizes, int n_in,
                              void* d_out, int out_size, void* d_ws, size_t ws_size,
                              hipStream_t stream) {
    char* wsb = (char*)d_ws;
    float* out = (float*)d_out;

    Params P;
    P.x    = (const float*)d_in[2];
    P.v    = (const float*)d_in[3];
    P.nf   = (const float*)d_in[0];
    P.edge = (const float*)d_in[1];
    P.e0w1 = (const float*)d_in[4];  P.e0b1 = (const float*)d_in[5];
    P.e0w2 = (const float*)d_in[6];  P.e0b2 = (const float*)d_in[7];
    P.n0w1 = (const float*)d_in[8];  P.n0b1 = (const float*)d_in[9];
    P.n0w2 = (const float*)d_in[10]; P.n0b2 = (const float*)d_in[11];
    P.e1w1 = (const float*)d_in[12]; P.e1b1 = (const float*)d_in[13];
    P.e1w2 = (const float*)d_in[14]; P.e1b2 = (const float*)d_in[15];
    P.n1w1 = (const float*)d_in[16]; P.n1b1 = (const float*)d_in[17];
    P.n1w2 = (const float*)d_in[18]; P.n1b2 = (const float*)d_in[19];
    P.dw1  = (const float*)d_in[20]; P.db1  = (const float*)d_in[21];
    P.dw2  = (const float*)d_in[22]; P.db2  = (const float*)d_in[23];
    P.vw1  = (const float*)d_in[24]; P.vb1  = (const float*)d_in[25];
    P.vw2  = (const float*)d_in[26]; P.vb2  = (const float*)d_in[27];

    P.CNT  = (unsigned*)wsb;                       // 256 B (barrier counter)
    P.FRg  = (float*)(wsb + 256);                  // 48 B
    P.H0   = (float*)(wsb + 512);                  // 229376 B
    P.HA   = (float*)(wsb + 512 + 229376);         // 524288 B
    P.HB   = (float*)(wsb + 512 + 229376 + 524288);
    char* p = wsb + 512 + 229376 + 524288 + 524288;
    P.PJF0 = (_Float16*)p;  p += 262144;
    P.PIH0 = (_Float16*)p;  p += 262144;
    P.PJF1 = (_Float16*)p;  p += 262144;
    P.PIH1 = (_Float16*)p;  p += 262144;
    P.WEH0 = (_Float16*)p;  p += 256;
    P.WEH1 = (_Float16*)p;  p += 256;
    P.W2F0 = (_Float16*)p;  p += 2048;
    P.W2F1 = (_Float16*)p;  p += 2048;

    P.out_h    = out;
    P.out_edge = out + 16384;
    P.out_x    = out + 278528;
    P.out_v    = out + 280064;

    // Zero the barrier counter (d_ws is poisoned 0xAA before every launch).
    hipMemsetAsync(P.CNT, 0, 256, stream);
    mega_kernel<<<1024, 256, 0, stream>>>(P);
}